// Round 18
// baseline (103.972 us; speedup 1.0000x reference)
//
#include <hip/hip_runtime.h>
#include <hip/hip_bf16.h>

#define NTOK 8192
#define DIM 2048
#define EXP 8
#define RK 64
#define OUTD 2048
#define SCALING (1.0f / 64.0f)
#define TTILE 64
#define MAXTILES (NTOK / TTILE) /* 128 */
#define JBINS 2                 /* step-B column split across blockIdx.y */
#define BK 128                  /* K-chunk (floats) staged per iteration */

typedef __attribute__((ext_vector_type(8))) short bf16x8;
typedef __attribute__((ext_vector_type(4))) short s16x4;
typedef __attribute__((ext_vector_type(4))) float f32x4;

__device__ __forceinline__ short f2bf(float f) {
    return __builtin_bit_cast(short, __float2bfloat16(f));
}

__device__ __forceinline__ bf16x8 load_cvt8(const float* __restrict__ p) {
    const float4 a = *(const float4*)(p);
    const float4 b = *(const float4*)(p + 4);
    bf16x8 r;
    r[0] = f2bf(a.x); r[1] = f2bf(a.y); r[2] = f2bf(a.z); r[3] = f2bf(a.w);
    r[4] = f2bf(b.x); r[5] = f2bf(b.y); r[6] = f2bf(b.z); r[7] = f2bf(b.w);
    return r;
}

__global__ void init_counts(int* __restrict__ counts) {
    if (threadIdx.x < EXP) counts[threadIdx.x] = 0;
}

// Router v8 (R17-verbatim; ~23us): v7 LDS-aggregated atomic tail + LDS-staged
// Wr + X register double-buffer. FMA/butterfly/softmax v1-verbatim.
__global__ __launch_bounds__(512) void router_kernel(
    const float* __restrict__ X, const float* __restrict__ Wr,
    const float* __restrict__ br, int* __restrict__ counts,
    float* __restrict__ wts, int* __restrict__ bucket) {
    __shared__ float4 Wlds[EXP * 512];  // 64 KB
    __shared__ int ecnt[EXP];
    __shared__ int ebase[EXP];
    const int tid = threadIdx.x;
    const float4* W4 = (const float4*)Wr;
#pragma unroll
    for (int j = 0; j < 8; ++j) Wlds[tid + 512 * j] = W4[tid + 512 * j];
    if (tid < EXP) ecnt[tid] = 0;
    __syncthreads();

    const int wave = (blockIdx.x * 512 + tid) >> 6;
    const int lane = tid & 63;
    const int t0 = wave * 4;

    double acc[4][EXP];
#pragma unroll
    for (int t = 0; t < 4; ++t)
#pragma unroll
        for (int e = 0; e < EXP; ++e) acc[t][e] = 0.0;

    const float4* X4 = (const float4*)X;
    float4 xc0, xc1, xc2, xc3, xn0, xn1, xn2, xn3;
    xc0 = X4[(size_t)(t0 + 0) * 512 + lane];
    xc1 = X4[(size_t)(t0 + 1) * 512 + lane];
    xc2 = X4[(size_t)(t0 + 2) * 512 + lane];
    xc3 = X4[(size_t)(t0 + 3) * 512 + lane];

#pragma unroll
    for (int i = 0; i < 8; ++i) {
        if (i < 7) {
            const int cn = lane + 64 * (i + 1);
            xn0 = X4[(size_t)(t0 + 0) * 512 + cn];
            xn1 = X4[(size_t)(t0 + 1) * 512 + cn];
            xn2 = X4[(size_t)(t0 + 2) * 512 + cn];
            xn3 = X4[(size_t)(t0 + 3) * 512 + cn];
        }
        const int c = lane + 64 * i;
#pragma unroll
        for (int e = 0; e < EXP; ++e) {
            const float4 wv = Wlds[e * 512 + c];
            acc[0][e] += (double)xc0.x * wv.x + (double)xc0.y * wv.y +
                         (double)xc0.z * wv.z + (double)xc0.w * wv.w;
            acc[1][e] += (double)xc1.x * wv.x + (double)xc1.y * wv.y +
                         (double)xc1.z * wv.z + (double)xc1.w * wv.w;
            acc[2][e] += (double)xc2.x * wv.x + (double)xc2.y * wv.y +
                         (double)xc2.z * wv.z + (double)xc2.w * wv.w;
            acc[3][e] += (double)xc3.x * wv.x + (double)xc3.y * wv.y +
                         (double)xc3.z * wv.z + (double)xc3.w * wv.w;
        }
        xc0 = xn0; xc1 = xn1; xc2 = xn2; xc3 = xn3;
    }

#pragma unroll
    for (int t = 0; t < 4; ++t)
#pragma unroll
        for (int e = 0; e < EXP; ++e) {
            double v = acc[t][e];
#pragma unroll
            for (int off = 32; off >= 1; off >>= 1) v += __shfl_xor(v, off, 64);
            acc[t][e] = v;
        }

    __syncthreads();  // all waves past Wlds reads; ecnt ready

    int n_l = -1, bi_l = 0, rank_l = 0;
#pragma unroll
    for (int t = 0; t < 4; ++t) {
        if (lane == t) {
            double lg[EXP];
#pragma unroll
            for (int e = 0; e < EXP; ++e) lg[e] = acc[t][e] + (double)br[e];
            double m = lg[0];
            int bi = 0;
#pragma unroll
            for (int e = 1; e < EXP; ++e)
                if (lg[e] > m) { m = lg[e]; bi = e; }
            float s = 0.f;
#pragma unroll
            for (int e = 0; e < EXP; ++e) s += __expf((float)(lg[e] - m));
            n_l = t0 + t;
            bi_l = bi;
            wts[n_l] = 1.0f / s;  // max softmax prob
            rank_l = atomicAdd(&ecnt[bi], 1);  // LDS atomic: local rank
        }
    }
    __syncthreads();
    if (tid < EXP) ebase[tid] = (ecnt[tid] > 0) ? atomicAdd(&counts[tid], ecnt[tid]) : 0;
    __syncthreads();
    if (n_l >= 0) bucket[bi_l * NTOK + ebase[bi_l] + rank_l] = n_l;
}

// Grouped LoRA v2: TTILE=64 (the R16 winner vs R17's 32) restructured to
// 512 threads / 8 waves. R16/R17 diagnosis: ~264 working blocks -> 1 block/CU
// -> 1 wave/SIMD, so the 16-chunk barrier pipeline had zero per-SIMD overlap.
// 8 waves = 2 waves/SIMD inside the block + per-thread staging halved
// (4+4 float4/chunk). Step A: wave wv owns (r-block wv&3, token-half wv>>2).
// Step B: wave wv takes n-tiles wv+8j. Per-token K accumulation order and
// all fragment mappings unchanged -> bit-identical output (canary 6.103516e-05).
__global__ __launch_bounds__(512, 2) void moe_lora_kernel(
    const float* __restrict__ X, const float* __restrict__ A,
    const float* __restrict__ B, const int* __restrict__ counts,
    const float* __restrict__ wts, const int* __restrict__ bucket,
    float* __restrict__ out) {
    const int e = blockIdx.x >> 7;       // MAXTILES == 128
    const int tile = blockIdx.x & 127;
    const int jbin = blockIdx.y;         // 0..JBINS-1, column half
    const int cnt = counts[e];
    const int base = tile * TTILE;
    if (base >= cnt) return;
    const int nt = min(TTILE, cnt - base);

    __shared__ int toks[TTILE];
    __shared__ float wt_s[TTILE];
    __shared__ short Xs[TTILE * BK];  // 64 rows x 128 bf16, swizzled, 16 KB
    __shared__ short As[RK * BK];     // 64 rows x 128 bf16, swizzled, 16 KB
    __shared__ short Hs[TTILE * RK];  // 64 x 64 bf16 h, XOR-swizzled, 8 KB

    const int tid = threadIdx.x;
    if (tid < TTILE) {
        const int tk = bucket[e * NTOK + base + min(tid, nt - 1)];
        toks[tid] = tk;
        wt_s[tid] = wts[tk];
    }
    __syncthreads();

    const int wv = tid >> 6;     // wave 0..7
    const int lane = tid & 63;
    const int lrow = lane & 15;  // M/N index within fragment
    const int lk = lane >> 4;    // k-block 0..3
    const int rblk = wv & 3;     // step-A r-block owner
    const int mh = wv >> 2;      // step-A token-half owner (tokens mh*32..+32)

    // ---- Step A: h[64][64] = Xtile @ A[e]^T, LDS-staged, reg-prefetched ----
    const float* Ae = A + (size_t)e * RK * DIM;
    const int scol = (tid & 31) * 4;   // f32 col within chunk (0..124)
    const int srow = tid >> 5;         // 0..15

    f32x4 hacc[2];
#pragma unroll
    for (int mm = 0; mm < 2; ++mm) hacc[mm] = (f32x4){0.f, 0.f, 0.f, 0.f};

    float4 xrA[4], arA[4], xrB[4], arB[4];

#define ISSUE(XR, AR, CH)                                                      \
    {                                                                          \
        const int k0_ = (CH)*BK;                                               \
        _Pragma("unroll") for (int i = 0; i < 4; ++i) {                        \
            const int row = i * 16 + srow;                                     \
            XR[i] = *(const float4*)(X + (size_t)toks[row] * DIM + k0_ + scol);\
            AR[i] = *(const float4*)(Ae + (size_t)row * DIM + k0_ + scol);     \
        }                                                                      \
    }

#define STAGE(XR, AR)                                                          \
    {                                                                          \
        _Pragma("unroll") for (int i = 0; i < 4; ++i) {                        \
            const int row = i * 16 + srow;                                     \
            s16x4 hx = {f2bf(XR[i].x), f2bf(XR[i].y), f2bf(XR[i].z),           \
                        f2bf(XR[i].w)};                                        \
            *(s16x4*)((char*)Xs + ((row * 256 + scol * 2) ^ ((row & 7) << 4))) = hx; \
            s16x4 ha = {f2bf(AR[i].x), f2bf(AR[i].y), f2bf(AR[i].z),           \
                        f2bf(AR[i].w)};                                        \
            *(s16x4*)((char*)As + ((row * 256 + scol * 2) ^ ((row & 7) << 4))) = ha; \
        }                                                                      \
    }

#define MFMA_CHUNK()                                                           \
    {                                                                          \
        _Pragma("unroll") for (int kk = 0; kk < 4; ++kk) {                     \
            const int cb = kk * 64 + lk * 16;                                  \
            const int ar_ = rblk * 16 + lrow;                                  \
            const bf16x8 af = *(const bf16x8*)((char*)As +                     \
                ((ar_ * 256 + cb) ^ ((ar_ & 7) << 4)));                        \
            _Pragma("unroll") for (int mm = 0; mm < 2; ++mm) {                 \
                const int xr_ = (mh * 2 + mm) * 16 + lrow;                     \
                const bf16x8 xf = *(const bf16x8*)((char*)Xs +                 \
                    ((xr_ * 256 + cb) ^ ((xr_ & 7) << 4)));                    \
                hacc[mm] = __builtin_amdgcn_mfma_f32_16x16x32_bf16(            \
                    xf, af, hacc[mm], 0, 0, 0);                                \
            }                                                                  \
        }                                                                      \
    }

    ISSUE(xrA, arA, 0);
#pragma unroll 1
    for (int ch = 0; ch < DIM / BK; ch += 2) {
        __syncthreads();              // prior MFMA done with LDS
        STAGE(xrA, arA);
        ISSUE(xrB, arB, ch + 1);      // prefetch odd chunk
        __syncthreads();
        MFMA_CHUNK();                 // even chunk

        __syncthreads();
        STAGE(xrB, arB);
        if (ch + 2 < DIM / BK) ISSUE(xrA, arA, ch + 2);  // prefetch next even
        __syncthreads();
        MFMA_CHUNK();                 // odd chunk
    }
#undef ISSUE
#undef STAGE
#undef MFMA_CHUNK

    // write h to LDS as bf16, XOR-swizzled rows of 64 bf16 (128 B)
#pragma unroll
    for (int mm = 0; mm < 2; ++mm) {
#pragma unroll
        for (int reg = 0; reg < 4; ++reg) {
            const int t = (mh * 2 + mm) * 16 + lk * 4 + reg;
            const int r = rblk * 16 + lrow;
            const int byte = ((t * RK + r) * 2) ^ ((t & 7) << 4);
            *(short*)((char*)Hs + byte) = f2bf(hacc[mm][reg]);
        }
    }
    __syncthreads();

    // ---- Step B: y[64][1024-chunk] = h @ B[e]^T, scale, scatter ----
    bf16x8 hf[4][2];
#pragma unroll
    for (int m = 0; m < 4; ++m)
#pragma unroll
        for (int k2 = 0; k2 < 2; ++k2) {
            const int t = m * 16 + lrow;
            const int r = k2 * 32 + lk * 8;
            const int byte = ((t * RK + r) * 2) ^ ((t & 7) << 4);
            hf[m][k2] = *(const bf16x8*)((char*)Hs + byte);
        }

    float scl[4][4];
    int trow[4][4];
    bool tok_ok[4][4];
#pragma unroll
    for (int m = 0; m < 4; ++m)
#pragma unroll
        for (int reg = 0; reg < 4; ++reg) {
            const int t = m * 16 + lk * 4 + reg;
            scl[m][reg] = SCALING * wt_s[t];
            trow[m][reg] = toks[t];
            tok_ok[m][reg] = (t < nt);
        }

    const float* Be = B + (size_t)e * OUTD * RK;
    const int j0 = jbin * 8;  // 8 j's per wave per bin; n-tile = wv + 8*j
    for (int j = j0; j < j0 + 8; ++j) {
        const int n = (wv + 8 * j) * 16;
        f32x4 yacc[4];
#pragma unroll
        for (int m = 0; m < 4; ++m) yacc[m] = (f32x4){0.f, 0.f, 0.f, 0.f};
#pragma unroll
        for (int k2 = 0; k2 < 2; ++k2) {
            const bf16x8 bf =
                load_cvt8(Be + (size_t)(n + lrow) * RK + k2 * 32 + lk * 8);
#pragma unroll
            for (int m = 0; m < 4; ++m)
                yacc[m] = __builtin_amdgcn_mfma_f32_16x16x32_bf16(hf[m][k2], bf, yacc[m], 0, 0, 0);
        }
#pragma unroll
        for (int m = 0; m < 4; ++m) {
#pragma unroll
            for (int reg = 0; reg < 4; ++reg) {
                if (tok_ok[m][reg]) {
                    const float y = yacc[m][reg] * scl[m][reg];
                    out[(size_t)trow[m][reg] * OUTD + n + lrow] = y;
                }
            }
        }
    }
}

extern "C" void kernel_launch(void* const* d_in, const int* in_sizes, int n_in,
                              void* d_out, int out_size, void* d_ws, size_t ws_size,
                              hipStream_t stream) {
    const float* X = (const float*)d_in[0];
    const float* A = (const float*)d_in[1];
    const float* B = (const float*)d_in[2];
    const float* Wr = (const float*)d_in[3];
    const float* br = (const float*)d_in[4];
    float* out = (float*)d_out;

    int* counts = (int*)d_ws;
    float* wts = (float*)((char*)d_ws + 64);
    int* bucket = (int*)((char*)d_ws + 64 + NTOK * 4);

    init_counts<<<1, 64, 0, stream>>>(counts);
    router_kernel<<<NTOK / 32, 512, 0, stream>>>(X, Wr, br, counts, wts, bucket);
    dim3 grid(EXP * MAXTILES, JBINS);
    moe_lora_kernel<<<grid, 512, 0, stream>>>(X, A, B, counts, wts, bucket, out);
}

// Round 19
// 90.986 us; speedup vs baseline: 1.1427x; 1.1427x over previous
//
#include <hip/hip_runtime.h>
#include <hip/hip_bf16.h>

#define NTOK 8192
#define DIM 2048
#define EXP 8
#define RK 64
#define OUTD 2048
#define SCALING (1.0f / 64.0f)
#define TTILE 64
#define MAXTILES (NTOK / TTILE) /* 128 */
#define JBINS 2                 /* step-B column split across blockIdx.y */
#define BK 128                  /* K-chunk (floats) staged per iteration */
#define MT (TTILE / 16)         /* 4 m-fragments per wave */

typedef __attribute__((ext_vector_type(8))) short bf16x8;
typedef __attribute__((ext_vector_type(4))) short s16x4;
typedef __attribute__((ext_vector_type(4))) float f32x4;

__device__ __forceinline__ short f2bf(float f) {
    return __builtin_bit_cast(short, __float2bfloat16(f));
}

__device__ __forceinline__ bf16x8 load_cvt8(const float* __restrict__ p) {
    const float4 a = *(const float4*)(p);
    const float4 b = *(const float4*)(p + 4);
    bf16x8 r;
    r[0] = f2bf(a.x); r[1] = f2bf(a.y); r[2] = f2bf(a.z); r[3] = f2bf(a.w);
    r[4] = f2bf(b.x); r[5] = f2bf(b.y); r[6] = f2bf(b.z); r[7] = f2bf(b.w);
    return r;
}

__global__ void init_counts(int* __restrict__ counts) {
    if (threadIdx.x < EXP) counts[threadIdx.x] = 0;
}

// Router v8 (R17-verbatim, ~22.7us): v7's LDS-aggregated atomic tail
// (R16: killed the 8192 same-address global-atomic serializer, 50->25us)
// + v5's memory body (LDS-staged Wr kills the 64 W-loads/wave L1 thrash;
// X register double-buffer keeps loads in flight under FMA — null at R14
// because the atomic tail masked it, real once the tail was fixed).
// FMA expression/order, butterfly, softmax: v1-verbatim -> bit-identical
// wts/counts/bucket-membership (slot order nondeterministic, proven harmless).
__global__ __launch_bounds__(512) void router_kernel(
    const float* __restrict__ X, const float* __restrict__ Wr,
    const float* __restrict__ br, int* __restrict__ counts,
    float* __restrict__ wts, int* __restrict__ bucket) {
    __shared__ float4 Wlds[EXP * 512];  // 64 KB
    __shared__ int ecnt[EXP];
    __shared__ int ebase[EXP];
    const int tid = threadIdx.x;
    const float4* W4 = (const float4*)Wr;
#pragma unroll
    for (int j = 0; j < 8; ++j) Wlds[tid + 512 * j] = W4[tid + 512 * j];
    if (tid < EXP) ecnt[tid] = 0;
    __syncthreads();

    const int wave = (blockIdx.x * 512 + tid) >> 6;
    const int lane = tid & 63;
    const int t0 = wave * 4;

    double acc[4][EXP];
#pragma unroll
    for (int t = 0; t < 4; ++t)
#pragma unroll
        for (int e = 0; e < EXP; ++e) acc[t][e] = 0.0;

    const float4* X4 = (const float4*)X;
    float4 xc0, xc1, xc2, xc3, xn0, xn1, xn2, xn3;
    xc0 = X4[(size_t)(t0 + 0) * 512 + lane];
    xc1 = X4[(size_t)(t0 + 1) * 512 + lane];
    xc2 = X4[(size_t)(t0 + 2) * 512 + lane];
    xc3 = X4[(size_t)(t0 + 3) * 512 + lane];

#pragma unroll
    for (int i = 0; i < 8; ++i) {
        if (i < 7) {
            const int cn = lane + 64 * (i + 1);
            xn0 = X4[(size_t)(t0 + 0) * 512 + cn];
            xn1 = X4[(size_t)(t0 + 1) * 512 + cn];
            xn2 = X4[(size_t)(t0 + 2) * 512 + cn];
            xn3 = X4[(size_t)(t0 + 3) * 512 + cn];
        }
        const int c = lane + 64 * i;
#pragma unroll
        for (int e = 0; e < EXP; ++e) {
            const float4 wv = Wlds[e * 512 + c];
            acc[0][e] += (double)xc0.x * wv.x + (double)xc0.y * wv.y +
                         (double)xc0.z * wv.z + (double)xc0.w * wv.w;
            acc[1][e] += (double)xc1.x * wv.x + (double)xc1.y * wv.y +
                         (double)xc1.z * wv.z + (double)xc1.w * wv.w;
            acc[2][e] += (double)xc2.x * wv.x + (double)xc2.y * wv.y +
                         (double)xc2.z * wv.z + (double)xc2.w * wv.w;
            acc[3][e] += (double)xc3.x * wv.x + (double)xc3.y * wv.y +
                         (double)xc3.z * wv.z + (double)xc3.w * wv.w;
        }
        xc0 = xn0; xc1 = xn1; xc2 = xn2; xc3 = xn3;
    }

    // full-wave butterfly reduce (all lanes end with the sum) — v1-verbatim
#pragma unroll
    for (int t = 0; t < 4; ++t)
#pragma unroll
        for (int e = 0; e < EXP; ++e) {
            double v = acc[t][e];
#pragma unroll
            for (int off = 32; off >= 1; off >>= 1) v += __shfl_xor(v, off, 64);
            acc[t][e] = v;
        }

    __syncthreads();  // all waves past Wlds reads; ecnt ready

    int n_l = -1, bi_l = 0, rank_l = 0;
#pragma unroll
    for (int t = 0; t < 4; ++t) {
        if (lane == t) {
            double lg[EXP];
#pragma unroll
            for (int e = 0; e < EXP; ++e) lg[e] = acc[t][e] + (double)br[e];
            double m = lg[0];
            int bi = 0;
#pragma unroll
            for (int e = 1; e < EXP; ++e)
                if (lg[e] > m) { m = lg[e]; bi = e; }
            float s = 0.f;
#pragma unroll
            for (int e = 0; e < EXP; ++e) s += __expf((float)(lg[e] - m));
            n_l = t0 + t;
            bi_l = bi;
            wts[n_l] = 1.0f / s;  // max softmax prob
            rank_l = atomicAdd(&ecnt[bi], 1);  // LDS atomic: local rank
        }
    }
    __syncthreads();
    if (tid < EXP) ebase[tid] = (ecnt[tid] > 0) ? atomicAdd(&counts[tid], ecnt[tid]) : 0;
    __syncthreads();
    if (n_l >= 0) bucket[bi_l * NTOK + ebase[bi_l] + rank_l] = n_l;
}

// Grouped LoRA (R13-VERBATIM — the measured local optimum at ~64us).
// Structure-space results: TTILE=32 (R17: +24% staging instrs, regressed),
// 8-wave/512-thr (R18: FETCH 69->115MB, regressed), lb(256,4) (R10 lesson:
// scratch spills). Register double-buffer prefetch of chunk ch+1's 16
// float4 loads under MFMA(ch) is the win that took 81->64us (R9).
__global__ __launch_bounds__(256, 2) void moe_lora_kernel(
    const float* __restrict__ X, const float* __restrict__ A,
    const float* __restrict__ B, const int* __restrict__ counts,
    const float* __restrict__ wts, const int* __restrict__ bucket,
    float* __restrict__ out) {
    const int e = blockIdx.x >> 7;       // MAXTILES == 128
    const int tile = blockIdx.x & 127;
    const int jbin = blockIdx.y;         // 0..JBINS-1, column half
    const int cnt = counts[e];
    const int base = tile * TTILE;
    if (base >= cnt) return;
    const int nt = min(TTILE, cnt - base);

    __shared__ int toks[TTILE];
    __shared__ float wt_s[TTILE];
    __shared__ short Xs[TTILE * BK];  // 64 rows x 128 bf16, swizzled, 16 KB
    __shared__ short As[RK * BK];     // 64 rows x 128 bf16, swizzled, 16 KB
    __shared__ short Hs[TTILE * RK];  // 64 x 64 bf16 h, XOR-swizzled, 8 KB

    const int tid = threadIdx.x;
    if (tid < TTILE) {
        const int tk = bucket[e * NTOK + base + min(tid, nt - 1)];
        toks[tid] = tk;
        wt_s[tid] = wts[tk];
    }
    __syncthreads();

    const int wv = tid >> 6;     // wave 0..3
    const int lane = tid & 63;
    const int lrow = lane & 15;  // M/N index within fragment
    const int lk = lane >> 4;    // k-block 0..3

    // ---- Step A: h[64][64] = Xtile @ A[e]^T, LDS-staged, reg-prefetched ----
    const float* Ae = A + (size_t)e * RK * DIM;
    const int scol = (tid & 31) * 4;   // f32 col within chunk (0..124)
    const int srow = tid >> 5;         // 0..7

    f32x4 hacc[MT];
#pragma unroll
    for (int m = 0; m < MT; ++m) hacc[m] = (f32x4){0.f, 0.f, 0.f, 0.f};

    float4 xrA[8], arA[8], xrB[8], arB[8];

#define ISSUE(XR, AR, CH)                                                      \
    {                                                                          \
        const int k0_ = (CH)*BK;                                               \
        _Pragma("unroll") for (int i = 0; i < 8; ++i) {                        \
            const int row = i * 8 + srow;                                      \
            XR[i] = *(const float4*)(X + (size_t)toks[row] * DIM + k0_ + scol);\
            AR[i] = *(const float4*)(Ae + (size_t)row * DIM + k0_ + scol);     \
        }                                                                      \
    }

#define STAGE(XR, AR)                                                          \
    {                                                                          \
        _Pragma("unroll") for (int i = 0; i < 8; ++i) {                        \
            const int row = i * 8 + srow;                                      \
            s16x4 hx = {f2bf(XR[i].x), f2bf(XR[i].y), f2bf(XR[i].z),           \
                        f2bf(XR[i].w)};                                        \
            *(s16x4*)((char*)Xs + ((row * 256 + scol * 2) ^ ((row & 7) << 4))) = hx; \
            s16x4 ha = {f2bf(AR[i].x), f2bf(AR[i].y), f2bf(AR[i].z),           \
                        f2bf(AR[i].w)};                                        \
            *(s16x4*)((char*)As + ((row * 256 + scol * 2) ^ ((row & 7) << 4))) = ha; \
        }                                                                      \
    }

#define MFMA_CHUNK()                                                           \
    {                                                                          \
        _Pragma("unroll") for (int kk = 0; kk < 4; ++kk) {                     \
            const int cb = kk * 64 + lk * 16;                                  \
            const int ar_ = wv * 16 + lrow;                                    \
            const bf16x8 af = *(const bf16x8*)((char*)As +                     \
                ((ar_ * 256 + cb) ^ ((ar_ & 7) << 4)));                        \
            _Pragma("unroll") for (int m = 0; m < MT; ++m) {                   \
                const int xr_ = m * 16 + lrow;                                 \
                const bf16x8 xf = *(const bf16x8*)((char*)Xs +                 \
                    ((xr_ * 256 + cb) ^ ((xr_ & 7) << 4)));                    \
                hacc[m] = __builtin_amdgcn_mfma_f32_16x16x32_bf16(             \
                    xf, af, hacc[m], 0, 0, 0);                                 \
            }                                                                  \
        }                                                                      \
    }

    ISSUE(xrA, arA, 0);
#pragma unroll 1
    for (int ch = 0; ch < DIM / BK; ch += 2) {
        __syncthreads();              // prior MFMA done with LDS
        STAGE(xrA, arA);
        ISSUE(xrB, arB, ch + 1);      // prefetch odd chunk
        __syncthreads();
        MFMA_CHUNK();                 // even chunk

        __syncthreads();
        STAGE(xrB, arB);
        if (ch + 2 < DIM / BK) ISSUE(xrA, arA, ch + 2);  // prefetch next even
        __syncthreads();
        MFMA_CHUNK();                 // odd chunk
    }
#undef ISSUE
#undef STAGE
#undef MFMA_CHUNK

    // write h to LDS as bf16, XOR-swizzled rows of 64 bf16 (128 B)
#pragma unroll
    for (int m = 0; m < MT; ++m) {
#pragma unroll
        for (int reg = 0; reg < 4; ++reg) {
            const int t = m * 16 + lk * 4 + reg;
            const int r = wv * 16 + lrow;
            const int byte = ((t * RK + r) * 2) ^ ((t & 7) << 4);
            *(short*)((char*)Hs + byte) = f2bf(hacc[m][reg]);
        }
    }
    __syncthreads();

    // ---- Step B: y[64][1024-chunk] = h @ B[e]^T, scale, scatter ----
    bf16x8 hf[MT][2];
#pragma unroll
    for (int m = 0; m < MT; ++m)
#pragma unroll
        for (int k2 = 0; k2 < 2; ++k2) {
            const int t = m * 16 + lrow;
            const int r = k2 * 32 + lk * 8;
            const int byte = ((t * RK + r) * 2) ^ ((t & 7) << 4);
            hf[m][k2] = *(const bf16x8*)((char*)Hs + byte);
        }

    float scl[MT][4];
    int trow[MT][4];
    bool tok_ok[MT][4];
#pragma unroll
    for (int m = 0; m < MT; ++m)
#pragma unroll
        for (int reg = 0; reg < 4; ++reg) {
            const int t = m * 16 + lk * 4 + reg;
            scl[m][reg] = SCALING * wt_s[t];
            trow[m][reg] = toks[t];
            tok_ok[m][reg] = (t < nt);
        }

    const float* Be = B + (size_t)e * OUTD * RK;
    const int j0 = jbin * (OUTD / 64 / JBINS);  // 16 j's per bin
    for (int j = j0; j < j0 + OUTD / 64 / JBINS; ++j) {
        const int n = (wv + 4 * j) * 16;
        f32x4 yacc[MT];
#pragma unroll
        for (int m = 0; m < MT; ++m) yacc[m] = (f32x4){0.f, 0.f, 0.f, 0.f};
#pragma unroll
        for (int k2 = 0; k2 < 2; ++k2) {
            const bf16x8 bf =
                load_cvt8(Be + (size_t)(n + lrow) * RK + k2 * 32 + lk * 8);
#pragma unroll
            for (int m = 0; m < MT; ++m)
                yacc[m] = __builtin_amdgcn_mfma_f32_16x16x32_bf16(hf[m][k2], bf, yacc[m], 0, 0, 0);
        }
#pragma unroll
        for (int m = 0; m < MT; ++m) {
#pragma unroll
            for (int reg = 0; reg < 4; ++reg) {
                if (tok_ok[m][reg]) {
                    const float y = yacc[m][reg] * scl[m][reg];
                    out[(size_t)trow[m][reg] * OUTD + n + lrow] = y;
                }
            }
        }
    }
}

extern "C" void kernel_launch(void* const* d_in, const int* in_sizes, int n_in,
                              void* d_out, int out_size, void* d_ws, size_t ws_size,
                              hipStream_t stream) {
    const float* X = (const float*)d_in[0];
    const float* A = (const float*)d_in[1];
    const float* B = (const float*)d_in[2];
    const float* Wr = (const float*)d_in[3];
    const float* br = (const float*)d_in[4];
    float* out = (float*)d_out;

    int* counts = (int*)d_ws;
    float* wts = (float*)((char*)d_ws + 64);
    int* bucket = (int*)((char*)d_ws + 64 + NTOK * 4);

    init_counts<<<1, 64, 0, stream>>>(counts);
    router_kernel<<<NTOK / 32, 512, 0, stream>>>(X, Wr, br, counts, wts, bucket);
    dim3 grid(EXP * MAXTILES, JBINS);
    moe_lora_kernel<<<grid, 256, 0, stream>>>(X, A, B, counts, wts, bucket, out);
}